// Round 15
// baseline (219.349 us; speedup 1.0000x reference)
//
#include <hip/hip_runtime.h>
#include <hip/hip_bf16.h>

#define N_PTS 4096
#define D_EMB 64
#define NPART 1024                                 // one partial-set per block

typedef __attribute__((ext_vector_type(8))) short bf16x8;  // 8 bf16 = 4 VGPR
typedef __attribute__((ext_vector_type(4))) float f32x4;   // MFMA 16x16 acc

// ---------------------------------------------------------------------------
// Prep (unchanged, verified): fragment-major bf16 hi/lo split + exact norms.
// ---------------------------------------------------------------------------
__global__ void prep_kernel(const float* __restrict__ mapping,
                            ushort* __restrict__ MhiT,
                            ushort* __restrict__ MloT,
                            float* __restrict__ nrm) {
  const int g = blockIdx.x;           // 16-row group 0..255
  const int l = threadIdx.x;          // 0..63
  const int r16 = l & 15, kg = l >> 4;
  float s = 0.f;
  #pragma unroll
  for (int ks = 0; ks < 2; ++ks) {
    bf16x8 vh, vl;
    #pragma unroll
    for (int j = 0; j < 8; ++j) {
      const int col = ks * 32 + kg * 8 + j;
      const float x = mapping[(g * 16 + r16) * D_EMB + col];
      s = fmaf(x, x, s);
      __hip_bfloat16 h = __float2bfloat16(x);
      const float hf = __bfloat162float(h);
      __hip_bfloat16 lo = __float2bfloat16(x - hf);
      vh[j] = (short)*reinterpret_cast<ushort*>(&h);
      vl[j] = (short)*reinterpret_cast<ushort*>(&lo);
    }
    const size_t base = ((size_t)(g * 2 + ks) * 64 + l) * 8;
    *(bf16x8*)(MhiT + base) = vh;
    *(bf16x8*)(MloT + base) = vl;
  }
  s += __shfl_xor(s, 16);
  s += __shfl_xor(s, 32);
  if (kg == 0) nrm[g * 16 + r16] = s;
}

// ---------------------------------------------------------------------------
// PROBE ROUND on the R14 structure (R14 = 30.4us total, best known).
//   MODE 0: full body (production when REPS=1; byte-identical to R14).
//   MODE 1: no-epilogue (loads + MFMA + transpose + keep-alive, rule 17).
//   MODE 2: loads-only (all global streams + keep-alive; no compute).
// REPS repeats the body; asm memory clobber per rep forces real re-issue.
// Pre-commit: f=full/rep, c=noepi/rep, m=loads/rep ->
//   m>=0.7f: memory-stream-bound -> attack b-frag redundancy / D path.
//   (c-m) dominant: MFMA/transpose chain -> 32x32 MFMA or drop transpose.
//   (f-c) dominant: epilogue VALU -> packed math / op-trim.
// ---------------------------------------------------------------------------
template <int MODE, int REPS>
__global__ __launch_bounds__(256) void distortion_main_t(
    const ushort* __restrict__ MhiT, const ushort* __restrict__ MloT,
    const float* __restrict__ Dm, const float* __restrict__ nrm,
    double* __restrict__ part) {
  __shared__ __align__(16) float sg[4][1024];   // wave-private 32x32 f32
  __shared__ float redv[16];                    // 4 waves x 4 sums

  const int t = threadIdx.x;
  const int w = t >> 6, l = t & 63;
  const int r16 = l & 15, kg = l >> 4;
  const int wr = w >> 1, wc = w & 1;
  const int I  = blockIdx.y * 64 + wr * 32;     // wave rows I..I+31
  const int Jb = blockIdx.x * 256 + wc * 32;    // wave col base; +jt*64
  const int jc8 = l & 7, is8 = l >> 3;

  float* sgw = sg[w];
  float s1 = 0.f, s2 = 0.f, s3 = 0.f, s4 = 0.f;  // accumulate ACROSS reps

  for (int rep = 0; rep < REPS; ++rep) {
    asm volatile("" ::: "memory");   // force re-issue of all loads each rep

    // ---- per-wave prologue: a-fragments + row norms
    bf16x8 aH[2][2], aL[2][2];
    #pragma unroll
    for (int ks = 0; ks < 2; ++ks)
      #pragma unroll
      for (int m = 0; m < 2; ++m) {
        const size_t fa = (((size_t)((I >> 4) + m) * 2 + ks) * 64 + l) * 8;
        aH[ks][m] = *(const bf16x8*)(MhiT + fa);
        aL[ks][m] = *(const bf16x8*)(MloT + fa);
      }
    float rA[4];
    #pragma unroll
    for (int it = 0; it < 4; ++it) rA[it] = nrm[I + it * 8 + is8];

    #pragma unroll
    for (int jt = 0; jt < 4; ++jt) {
      const int J = Jb + jt * 64;

      // ---- grouped loads for this tile
      bf16x8 bH[2][2], bL[2][2];
      #pragma unroll
      for (int ks = 0; ks < 2; ++ks)
        #pragma unroll
        for (int n = 0; n < 2; ++n) {
          const size_t fb = (((size_t)((J >> 4) + n) * 2 + ks) * 64 + l) * 8;
          bH[ks][n] = *(const bf16x8*)(MhiT + fb);
          bL[ks][n] = *(const bf16x8*)(MloT + fb);
        }
      float4 D4[4];
      #pragma unroll
      for (int it = 0; it < 4; ++it)
        D4[it] = *(const float4*)(Dm + (size_t)(I + it * 8 + is8) * N_PTS +
                                  J + jc8 * 4);
      const float4 rB4 = *(const float4*)(nrm + J + jc8 * 4);

      if constexpr (MODE == 2) {
        // keep every load live; no compute
        s1 += (float)bH[0][0][0] + (float)bL[0][0][0] +
              (float)bH[1][1][7] + (float)bL[1][1][7];
        s2 += D4[0].x + D4[1].y + D4[2].z + D4[3].w;
        s3 += rB4.x + rA[jt];
        s4 += (float)aH[0][0][0] + (float)aL[0][1][7];
        continue;
      }

      // ---- MFMA (swapped operands; layout HW-verified)
      f32x4 acc[2][2] = {};
      #pragma unroll
      for (int ks = 0; ks < 2; ++ks)
        #pragma unroll
        for (int m = 0; m < 2; ++m)
          #pragma unroll
          for (int n = 0; n < 2; ++n) {
            acc[m][n] = __builtin_amdgcn_mfma_f32_16x16x32_bf16(
                bH[ks][n], aH[ks][m], acc[m][n], 0, 0, 0);   // Hj.Hi
            acc[m][n] = __builtin_amdgcn_mfma_f32_16x16x32_bf16(
                bH[ks][n], aL[ks][m], acc[m][n], 0, 0, 0);   // Hj.Li
            acc[m][n] = __builtin_amdgcn_mfma_f32_16x16x32_bf16(
                bL[ks][n], aH[ks][m], acc[m][n], 0, 0, 0);   // Lj.Hi
          }

      // ---- wave-private transpose (no barrier)
      #pragma unroll
      for (int m = 0; m < 2; ++m) {
        const int i_loc = m * 16 + r16;
        #pragma unroll
        for (int n = 0; n < 2; ++n) {
          const int jc4 = n * 4 + kg;
          *(f32x4*)(sgw + i_loc * 32 + ((jc4 ^ (i_loc & 7)) << 2)) = acc[m][n];
        }
      }

      if constexpr (MODE == 1) {
        // keep transpose + D/rB loads live; skip epilogue math
        #pragma unroll
        for (int it = 0; it < 4; ++it) {
          const int i_loc = it * 8 + is8;
          const f32x4 g4 =
              *(const f32x4*)(sgw + i_loc * 32 + ((jc8 ^ (i_loc & 7)) << 2));
          s1 += g4[0];
          s2 += D4[it].x;
        }
        s3 += rB4.x + rA[jt];
      } else {
        // ---- full epilogue
        #pragma unroll
        for (int it = 0; it < 4; ++it) {
          const int i_loc = it * 8 + is8;
          const int gi = I + i_loc;
          const f32x4 g4 =
              *(const f32x4*)(sgw + i_loc * 32 + ((jc8 ^ (i_loc & 7)) << 2));
          const float4 Dv4 = D4[it];
          #pragma unroll
          for (int r = 0; r < 4; ++r) {
            const float Dv  = (r == 0) ? Dv4.x : (r == 1) ? Dv4.y : (r == 2) ? Dv4.z : Dv4.w;
            const float rB  = (r == 0) ? rB4.x : (r == 1) ? rB4.y : (r == 2) ? rB4.z : rB4.w;
            const float dot = g4[r];
            const float sq = fmaxf(rA[it] + rB - 2.f * dot, 0.f);
            float dd = __builtin_amdgcn_sqrtf(sq);
            const bool diag = (gi == J + jc8 * 4 + r);
            if (diag) dd = 0.f;                      // exact: ||x-x|| = 0
            const float denom = Dv + (diag ? 1.f : 0.f) + 1e-8f;
            const float rd = __builtin_amdgcn_rcpf(denom);
            const float av = dd * rd;                // a = d/denom
            const float bv = Dv * rd;                // b = D/denom
            s1 += av;
            s2 = fmaf(av, av, s2);
            s3 = fmaf(av, bv, s3);
            s4 = fmaf(bv, bv, s4);
          }
        }
      }
    }
  }

  // ---- one reduce per wave, block reduce, one write-set per block
  #pragma unroll
  for (int off = 32; off > 0; off >>= 1) {
    s1 += __shfl_down(s1, off);
    s2 += __shfl_down(s2, off);
    s3 += __shfl_down(s3, off);
    s4 += __shfl_down(s4, off);
  }
  if (l == 0) {
    redv[w * 4 + 0] = s1; redv[w * 4 + 1] = s2;
    redv[w * 4 + 2] = s3; redv[w * 4 + 3] = s4;
  }
  __syncthreads();
  if (t < 4) {
    const double v = (double)redv[0 * 4 + t] + (double)redv[1 * 4 + t] +
                     (double)redv[2 * 4 + t] + (double)redv[3 * 4 + t];
    const int bid = blockIdx.y * gridDim.x + blockIdx.x;
    part[t * NPART + bid] = v;
  }
}

// ---------------------------------------------------------------------------
// Reduce 4 x 1024 partials; emit s^2*S2 - 2 s S3 + S4, s = S1/S2.
// ---------------------------------------------------------------------------
__global__ __launch_bounds__(1024) void distortion_final(
    const double* __restrict__ part, float* __restrict__ out) {
  __shared__ double red[16][4];
  const int t = threadIdx.x;
  double s[4];
  #pragma unroll
  for (int k = 0; k < 4; ++k) s[k] = part[k * NPART + t];
  #pragma unroll
  for (int off = 32; off > 0; off >>= 1)
    #pragma unroll
    for (int k = 0; k < 4; ++k) s[k] += __shfl_down(s[k], off);
  const int w = t >> 6, l = t & 63;
  if (l == 0) {
    #pragma unroll
    for (int k = 0; k < 4; ++k) red[w][k] = s[k];
  }
  __syncthreads();
  if (t == 0) {
    double S0 = 0, S1 = 0, S2 = 0, S3 = 0;
    #pragma unroll
    for (int ww = 0; ww < 16; ++ww) {
      S0 += red[ww][0]; S1 += red[ww][1]; S2 += red[ww][2]; S3 += red[ww][3];
    }
    const double sc = S0 / S1;
    const double r = (sc * sc * S1 - 2.0 * sc * S2 + S3) /
                     ((double)N_PTS * (double)N_PTS - (double)N_PTS);
    out[0] = (float)r;
  }
}

extern "C" void kernel_launch(void* const* d_in, const int* in_sizes, int n_in,
                              void* d_out, int out_size, void* d_ws, size_t ws_size,
                              hipStream_t stream) {
  const float* mapping = (const float*)d_in[0];
  const float* Dm = (const float*)d_in[1];
  float* out = (float*)d_out;
  // ws: nrm 16K | part 32K | MhiT 512K | MloT 512K | probes 3x32K
  char* p = (char*)d_ws;
  float* nrm = (float*)p;
  double* part = (double*)(p + 16384);
  ushort* MhiT = (ushort*)(p + 16384 + 32768);
  ushort* MloT = (ushort*)(p + 16384 + 32768 + 524288);
  double* probeA = (double*)(p + 16384 + 32768 + 524288 + 524288);
  double* probeB = (double*)(p + 16384 + 32768 + 524288 + 524288 + 32768);
  double* probeC = (double*)(p + 16384 + 32768 + 524288 + 524288 + 65536);

  const dim3 grid(16, 64);
  prep_kernel<<<dim3(N_PTS / 16), dim3(64), 0, stream>>>(mapping, MhiT, MloT, nrm);
  distortion_main_t<0, 1><<<grid, dim3(256), 0, stream>>>(MhiT, MloT, Dm, nrm, part);
  distortion_final<<<1, 1024, 0, stream>>>(part, out);
  // probes (scratch outputs; REPS makes them visible over ~40us fills)
  distortion_main_t<0, 3><<<grid, dim3(256), 0, stream>>>(MhiT, MloT, Dm, nrm, probeA);
  distortion_main_t<1, 5><<<grid, dim3(256), 0, stream>>>(MhiT, MloT, Dm, nrm, probeB);
  distortion_main_t<2, 8><<<grid, dim3(256), 0, stream>>>(MhiT, MloT, Dm, nrm, probeC);
}

// Round 16
// 31.722 us; speedup vs baseline: 6.9146x; 6.9146x over previous
//
#include <hip/hip_runtime.h>
#include <hip/hip_bf16.h>

#define N_PTS 4096
#define D_EMB 64
#define NPART 1024                                 // one partial-set per block

typedef __attribute__((ext_vector_type(8))) short bf16x8;  // 8 bf16 = 4 VGPR
typedef __attribute__((ext_vector_type(4))) float f32x4;   // MFMA 16x16 acc

// ---------------------------------------------------------------------------
// Prep (unchanged, verified): fragment-major bf16 hi/lo split + exact norms.
// ---------------------------------------------------------------------------
__global__ void prep_kernel(const float* __restrict__ mapping,
                            ushort* __restrict__ MhiT,
                            ushort* __restrict__ MloT,
                            float* __restrict__ nrm) {
  const int g = blockIdx.x;           // 16-row group 0..255
  const int l = threadIdx.x;          // 0..63
  const int r16 = l & 15, kg = l >> 4;
  float s = 0.f;
  #pragma unroll
  for (int ks = 0; ks < 2; ++ks) {
    bf16x8 vh, vl;
    #pragma unroll
    for (int j = 0; j < 8; ++j) {
      const int col = ks * 32 + kg * 8 + j;
      const float x = mapping[(g * 16 + r16) * D_EMB + col];
      s = fmaf(x, x, s);
      __hip_bfloat16 h = __float2bfloat16(x);
      const float hf = __bfloat162float(h);
      __hip_bfloat16 lo = __float2bfloat16(x - hf);
      vh[j] = (short)*reinterpret_cast<ushort*>(&h);
      vl[j] = (short)*reinterpret_cast<ushort*>(&lo);
    }
    const size_t base = ((size_t)(g * 2 + ks) * 64 + l) * 8;
    *(bf16x8*)(MhiT + base) = vh;
    *(bf16x8*)(MloT + base) = vl;
  }
  s += __shfl_xor(s, 16);
  s += __shfl_xor(s, 32);
  if (kg == 0) nrm[g * 16 + r16] = s;
}

// ---------------------------------------------------------------------------
// R14 structure + within-wave T14 pipeline.
// dot = Hj.Hi + Hj.Li + Lj.Hi (absmax 0.0 since R6).
//
// R15 probe decomposition (loads m=10.9us/rep, no-epi c~=m, full f~=18.5):
// MFMA+transpose are fully hidden; the EPILOGUE added ~7.6us because it ran
// AFTER each tile's loads, serialized. THIS round: D/rB for tile jt+1 are
// prefetched into a register double-buffer BEFORE tile jt's epilogue, so
// the ~480cyc epilogue VALU covers the next tile's memory latency.
// Per jt: [issue b(jt)] [issue D/rB(jt+1)->buf^1] [MFMA jt] [transpose jt]
//         [epilogue jt from buf] — full unroll, compile-time buffer indices
// (rule 20). Everything else identical to R14 (best known, 30.4us).
// ---------------------------------------------------------------------------
__global__ __launch_bounds__(256) void distortion_main(
    const ushort* __restrict__ MhiT, const ushort* __restrict__ MloT,
    const float* __restrict__ Dm, const float* __restrict__ nrm,
    double* __restrict__ part) {
  __shared__ __align__(16) float sg[4][1024];   // wave-private 32x32 f32
  __shared__ float redv[16];                    // 4 waves x 4 sums

  const int t = threadIdx.x;
  const int w = t >> 6, l = t & 63;
  const int r16 = l & 15, kg = l >> 4;
  const int wr = w >> 1, wc = w & 1;
  const int I  = blockIdx.y * 64 + wr * 32;     // wave rows I..I+31
  const int Jb = blockIdx.x * 256 + wc * 32;    // wave col base; +jt*64
  const int jc8 = l & 7, is8 = l >> 3;

  // ---- per-wave constants: a-fragments + row norms (loaded ONCE)
  bf16x8 aH[2][2], aL[2][2];                    // [ks][m]
  #pragma unroll
  for (int ks = 0; ks < 2; ++ks)
    #pragma unroll
    for (int m = 0; m < 2; ++m) {
      const size_t fa = (((size_t)((I >> 4) + m) * 2 + ks) * 64 + l) * 8;
      aH[ks][m] = *(const bf16x8*)(MhiT + fa);
      aL[ks][m] = *(const bf16x8*)(MloT + fa);
    }
  float rA[4];
  #pragma unroll
  for (int it = 0; it < 4; ++it) rA[it] = nrm[I + it * 8 + is8];

  float* sgw = sg[w];
  float s1 = 0.f, s2 = 0.f, s3 = 0.f, s4 = 0.f;

  // ---- D/rB register double-buffer; preload tile 0
  float4 D4[2][4];
  float4 rB4[2];
  #pragma unroll
  for (int it = 0; it < 4; ++it)
    D4[0][it] = *(const float4*)(Dm + (size_t)(I + it * 8 + is8) * N_PTS +
                                 Jb + jc8 * 4);
  rB4[0] = *(const float4*)(nrm + Jb + jc8 * 4);

  #pragma unroll
  for (int jt = 0; jt < 4; ++jt) {
    const int cur = jt & 1, nxt = cur ^ 1;      // compile-time after unroll
    const int J = Jb + jt * 64;

    // ---- issue b-frag loads for THIS tile (L2-resident stream)
    bf16x8 bH[2][2], bL[2][2];
    #pragma unroll
    for (int ks = 0; ks < 2; ++ks)
      #pragma unroll
      for (int n = 0; n < 2; ++n) {
        const size_t fb = (((size_t)((J >> 4) + n) * 2 + ks) * 64 + l) * 8;
        bH[ks][n] = *(const bf16x8*)(MhiT + fb);
        bL[ks][n] = *(const bf16x8*)(MloT + fb);
      }

    // ---- issue D/rB prefetch for NEXT tile (HBM/L3 stream, long pole)
    if (jt < 3) {
      const int Jn = J + 64;
      #pragma unroll
      for (int it = 0; it < 4; ++it)
        D4[nxt][it] = *(const float4*)(Dm + (size_t)(I + it * 8 + is8) * N_PTS +
                                       Jn + jc8 * 4);
      rB4[nxt] = *(const float4*)(nrm + Jn + jc8 * 4);
    }

    // ---- MFMA (swapped operands; layout HW-verified)
    f32x4 acc[2][2] = {};
    #pragma unroll
    for (int ks = 0; ks < 2; ++ks)
      #pragma unroll
      for (int m = 0; m < 2; ++m)
        #pragma unroll
        for (int n = 0; n < 2; ++n) {
          acc[m][n] = __builtin_amdgcn_mfma_f32_16x16x32_bf16(
              bH[ks][n], aH[ks][m], acc[m][n], 0, 0, 0);   // Hj.Hi
          acc[m][n] = __builtin_amdgcn_mfma_f32_16x16x32_bf16(
              bH[ks][n], aL[ks][m], acc[m][n], 0, 0, 0);   // Hj.Li
          acc[m][n] = __builtin_amdgcn_mfma_f32_16x16x32_bf16(
              bL[ks][n], aH[ks][m], acc[m][n], 0, 0, 0);   // Lj.Hi
        }

    // ---- wave-private transpose (no barrier; in-order DS within wave)
    #pragma unroll
    for (int m = 0; m < 2; ++m) {
      const int i_loc = m * 16 + r16;
      #pragma unroll
      for (int n = 0; n < 2; ++n) {
        const int jc4 = n * 4 + kg;
        *(f32x4*)(sgw + i_loc * 32 + ((jc4 ^ (i_loc & 7)) << 2)) = acc[m][n];
      }
    }

    // ---- epilogue for THIS tile; next tile's D/rB already in flight
    #pragma unroll
    for (int it = 0; it < 4; ++it) {
      const int i_loc = it * 8 + is8;
      const int gi = I + i_loc;
      const f32x4 g4 =
          *(const f32x4*)(sgw + i_loc * 32 + ((jc8 ^ (i_loc & 7)) << 2));
      const float4 Dv4 = D4[cur][it];
      const float4 rBt = rB4[cur];
      #pragma unroll
      for (int r = 0; r < 4; ++r) {
        const float Dv  = (r == 0) ? Dv4.x : (r == 1) ? Dv4.y : (r == 2) ? Dv4.z : Dv4.w;
        const float rB  = (r == 0) ? rBt.x : (r == 1) ? rBt.y : (r == 2) ? rBt.z : rBt.w;
        const float dot = g4[r];
        const float sq = fmaxf(rA[it] + rB - 2.f * dot, 0.f);
        float dd = __builtin_amdgcn_sqrtf(sq);
        const bool diag = (gi == J + jc8 * 4 + r);
        if (diag) dd = 0.f;                      // exact: ||x-x|| = 0
        const float denom = Dv + (diag ? 1.f : 0.f) + 1e-8f;
        const float rd = __builtin_amdgcn_rcpf(denom);
        const float av = dd * rd;                // a = d/denom
        const float bv = Dv * rd;                // b = D/denom
        s1 += av;
        s2 = fmaf(av, av, s2);
        s3 = fmaf(av, bv, s3);
        s4 = fmaf(bv, bv, s4);
      }
    }
  }

  // ---- one reduce per wave, block reduce, one write-set per block
  #pragma unroll
  for (int off = 32; off > 0; off >>= 1) {
    s1 += __shfl_down(s1, off);
    s2 += __shfl_down(s2, off);
    s3 += __shfl_down(s3, off);
    s4 += __shfl_down(s4, off);
  }
  if (l == 0) {
    redv[w * 4 + 0] = s1; redv[w * 4 + 1] = s2;
    redv[w * 4 + 2] = s3; redv[w * 4 + 3] = s4;
  }
  __syncthreads();
  if (t < 4) {
    const double v = (double)redv[0 * 4 + t] + (double)redv[1 * 4 + t] +
                     (double)redv[2 * 4 + t] + (double)redv[3 * 4 + t];
    const int bid = blockIdx.y * gridDim.x + blockIdx.x;
    part[t * NPART + bid] = v;
  }
}

// ---------------------------------------------------------------------------
// Reduce 4 x 1024 partials; emit s^2*S2 - 2 s S3 + S4, s = S1/S2.
// ---------------------------------------------------------------------------
__global__ __launch_bounds__(1024) void distortion_final(
    const double* __restrict__ part, float* __restrict__ out) {
  __shared__ double red[16][4];
  const int t = threadIdx.x;
  double s[4];
  #pragma unroll
  for (int k = 0; k < 4; ++k) s[k] = part[k * NPART + t];
  #pragma unroll
  for (int off = 32; off > 0; off >>= 1)
    #pragma unroll
    for (int k = 0; k < 4; ++k) s[k] += __shfl_down(s[k], off);
  const int w = t >> 6, l = t & 63;
  if (l == 0) {
    #pragma unroll
    for (int k = 0; k < 4; ++k) red[w][k] = s[k];
  }
  __syncthreads();
  if (t == 0) {
    double S0 = 0, S1 = 0, S2 = 0, S3 = 0;
    #pragma unroll
    for (int ww = 0; ww < 16; ++ww) {
      S0 += red[ww][0]; S1 += red[ww][1]; S2 += red[ww][2]; S3 += red[ww][3];
    }
    const double sc = S0 / S1;
    const double r = (sc * sc * S1 - 2.0 * sc * S2 + S3) /
                     ((double)N_PTS * (double)N_PTS - (double)N_PTS);
    out[0] = (float)r;
  }
}

extern "C" void kernel_launch(void* const* d_in, const int* in_sizes, int n_in,
                              void* d_out, int out_size, void* d_ws, size_t ws_size,
                              hipStream_t stream) {
  const float* mapping = (const float*)d_in[0];
  const float* Dm = (const float*)d_in[1];
  float* out = (float*)d_out;
  // ws layout: nrm 16KB | part 32KB | MhiT 512KB | MloT 512KB (~1.07 MB)
  float* nrm = (float*)d_ws;
  double* part = (double*)((char*)d_ws + 16384);
  ushort* MhiT = (ushort*)((char*)d_ws + 16384 + 32768);
  ushort* MloT = (ushort*)((char*)d_ws + 16384 + 32768 + 524288);

  prep_kernel<<<dim3(N_PTS / 16), dim3(64), 0, stream>>>(mapping, MhiT, MloT, nrm);
  distortion_main<<<dim3(16, 64), dim3(256), 0, stream>>>(MhiT, MloT, Dm, nrm, part);
  distortion_final<<<1, 1024, 0, stream>>>(part, out);
}

// Round 17
// 30.269 us; speedup vs baseline: 7.2465x; 1.0480x over previous
//
#include <hip/hip_runtime.h>
#include <hip/hip_bf16.h>

#define N_PTS 4096
#define D_EMB 64
#define NPART 1024                                 // one partial-set per block

typedef __attribute__((ext_vector_type(8))) short bf16x8;  // 8 bf16 = 4 VGPR
typedef __attribute__((ext_vector_type(4))) float f32x4;   // MFMA 16x16 acc

// ---------------------------------------------------------------------------
// Prep (unchanged, verified): fragment-major bf16 hi/lo split + exact norms.
// ---------------------------------------------------------------------------
__global__ void prep_kernel(const float* __restrict__ mapping,
                            ushort* __restrict__ MhiT,
                            ushort* __restrict__ MloT,
                            float* __restrict__ nrm) {
  const int g = blockIdx.x;           // 16-row group 0..255
  const int l = threadIdx.x;          // 0..63
  const int r16 = l & 15, kg = l >> 4;
  float s = 0.f;
  #pragma unroll
  for (int ks = 0; ks < 2; ++ks) {
    bf16x8 vh, vl;
    #pragma unroll
    for (int j = 0; j < 8; ++j) {
      const int col = ks * 32 + kg * 8 + j;
      const float x = mapping[(g * 16 + r16) * D_EMB + col];
      s = fmaf(x, x, s);
      __hip_bfloat16 h = __float2bfloat16(x);
      const float hf = __bfloat162float(h);
      __hip_bfloat16 lo = __float2bfloat16(x - hf);
      vh[j] = (short)*reinterpret_cast<ushort*>(&h);
      vl[j] = (short)*reinterpret_cast<ushort*>(&lo);
    }
    const size_t base = ((size_t)(g * 2 + ks) * 64 + l) * 8;
    *(bf16x8*)(MhiT + base) = vh;
    *(bf16x8*)(MloT + base) = vl;
  }
  s += __shfl_xor(s, 16);
  s += __shfl_xor(s, 32);
  if (kg == 0) nrm[g * 16 + r16] = s;
}

// ---------------------------------------------------------------------------
// R14 structure (best known, 30.4us) with ONE change: drop the Lj.Hi MFMA
// term and its bL fragment loads.
//   dot = Hj.Hi + Hj.Li      (was + Lj.Hi; lo.lo dropped since R6)
// Error: dropped term sigma ~0.016 abs on d^2~128 -> d rel ~1.2e-4, zero
// bias -> final scalar moves ~1e-4 vs 2e-2 threshold (~100x margin).
// Why: R15 probes show the load stream m=10.9us/rep already at delivered-BW
// roofline (~6.2TB/s HBM+L3); exposed residue is latency at 4 waves/SIMD
// (VGPR ~110). Dropping bL: -64MB L2 fragment traffic (-33%), -16 VGPR
// (occupancy boundary 4->5 waves/SIMD), -8 MFMA/tile.
// R16 lesson: D-prefetch double-buffer regressed (VGPR cost) — reverted.
// R7 lesson: loads grouped at iteration top. R5: no atomics.
// R2/R3: no min-waves launch_bounds.
// ---------------------------------------------------------------------------
__global__ __launch_bounds__(256) void distortion_main(
    const ushort* __restrict__ MhiT, const ushort* __restrict__ MloT,
    const float* __restrict__ Dm, const float* __restrict__ nrm,
    double* __restrict__ part) {
  __shared__ __align__(16) float sg[4][1024];   // wave-private 32x32 f32
  __shared__ float redv[16];                    // 4 waves x 4 sums

  const int t = threadIdx.x;
  const int w = t >> 6, l = t & 63;
  const int r16 = l & 15, kg = l >> 4;
  const int wr = w >> 1, wc = w & 1;
  const int I  = blockIdx.y * 64 + wr * 32;     // wave rows I..I+31
  const int Jb = blockIdx.x * 256 + wc * 32;    // wave col base; +jt*64
  const int jc8 = l & 7, is8 = l >> 3;

  // ---- per-wave constants: a-fragments + row norms (loaded ONCE)
  bf16x8 aH[2][2], aL[2][2];                    // [ks][m]
  #pragma unroll
  for (int ks = 0; ks < 2; ++ks)
    #pragma unroll
    for (int m = 0; m < 2; ++m) {
      const size_t fa = (((size_t)((I >> 4) + m) * 2 + ks) * 64 + l) * 8;
      aH[ks][m] = *(const bf16x8*)(MhiT + fa);
      aL[ks][m] = *(const bf16x8*)(MloT + fa);
    }
  float rA[4];
  #pragma unroll
  for (int it = 0; it < 4; ++it) rA[it] = nrm[I + it * 8 + is8];

  float* sgw = sg[w];
  float s1 = 0.f, s2 = 0.f, s3 = 0.f, s4 = 0.f;

  #pragma unroll
  for (int jt = 0; jt < 4; ++jt) {
    const int J = Jb + jt * 64;

    // ---- grouped loads for this tile (bH only; bL dropped)
    bf16x8 bH[2][2];
    #pragma unroll
    for (int ks = 0; ks < 2; ++ks)
      #pragma unroll
      for (int n = 0; n < 2; ++n) {
        const size_t fb = (((size_t)((J >> 4) + n) * 2 + ks) * 64 + l) * 8;
        bH[ks][n] = *(const bf16x8*)(MhiT + fb);
      }
    float4 D4[4];
    #pragma unroll
    for (int it = 0; it < 4; ++it)
      D4[it] = *(const float4*)(Dm + (size_t)(I + it * 8 + is8) * N_PTS +
                                J + jc8 * 4);
    const float4 rB4 = *(const float4*)(nrm + J + jc8 * 4);

    // ---- MFMA (swapped operands; layout HW-verified)
    f32x4 acc[2][2] = {};
    #pragma unroll
    for (int ks = 0; ks < 2; ++ks)
      #pragma unroll
      for (int m = 0; m < 2; ++m)
        #pragma unroll
        for (int n = 0; n < 2; ++n) {
          acc[m][n] = __builtin_amdgcn_mfma_f32_16x16x32_bf16(
              bH[ks][n], aH[ks][m], acc[m][n], 0, 0, 0);   // Hj.Hi
          acc[m][n] = __builtin_amdgcn_mfma_f32_16x16x32_bf16(
              bH[ks][n], aL[ks][m], acc[m][n], 0, 0, 0);   // Hj.Li
        }

    // ---- wave-private transpose (no barrier; in-order DS within wave)
    #pragma unroll
    for (int m = 0; m < 2; ++m) {
      const int i_loc = m * 16 + r16;
      #pragma unroll
      for (int n = 0; n < 2; ++n) {
        const int jc4 = n * 4 + kg;
        *(f32x4*)(sgw + i_loc * 32 + ((jc4 ^ (i_loc & 7)) << 2)) = acc[m][n];
      }
    }

    // ---- epilogue: gram from LDS, D/norms from registers
    #pragma unroll
    for (int it = 0; it < 4; ++it) {
      const int i_loc = it * 8 + is8;
      const int gi = I + i_loc;
      const f32x4 g4 =
          *(const f32x4*)(sgw + i_loc * 32 + ((jc8 ^ (i_loc & 7)) << 2));
      const float4 Dv4 = D4[it];
      #pragma unroll
      for (int r = 0; r < 4; ++r) {
        const float Dv  = (r == 0) ? Dv4.x : (r == 1) ? Dv4.y : (r == 2) ? Dv4.z : Dv4.w;
        const float rB  = (r == 0) ? rB4.x : (r == 1) ? rB4.y : (r == 2) ? rB4.z : rB4.w;
        const float dot = g4[r];
        const float sq = fmaxf(rA[it] + rB - 2.f * dot, 0.f);
        float dd = __builtin_amdgcn_sqrtf(sq);
        const bool diag = (gi == J + jc8 * 4 + r);
        if (diag) dd = 0.f;                      // exact: ||x-x|| = 0
        const float denom = Dv + (diag ? 1.f : 0.f) + 1e-8f;
        const float rd = __builtin_amdgcn_rcpf(denom);
        const float av = dd * rd;                // a = d/denom
        const float bv = Dv * rd;                // b = D/denom
        s1 += av;
        s2 = fmaf(av, av, s2);
        s3 = fmaf(av, bv, s3);
        s4 = fmaf(bv, bv, s4);
      }
    }
  }

  // ---- one reduce per wave, block reduce, one write-set per block
  #pragma unroll
  for (int off = 32; off > 0; off >>= 1) {
    s1 += __shfl_down(s1, off);
    s2 += __shfl_down(s2, off);
    s3 += __shfl_down(s3, off);
    s4 += __shfl_down(s4, off);
  }
  if (l == 0) {
    redv[w * 4 + 0] = s1; redv[w * 4 + 1] = s2;
    redv[w * 4 + 2] = s3; redv[w * 4 + 3] = s4;
  }
  __syncthreads();
  if (t < 4) {
    const double v = (double)redv[0 * 4 + t] + (double)redv[1 * 4 + t] +
                     (double)redv[2 * 4 + t] + (double)redv[3 * 4 + t];
    const int bid = blockIdx.y * gridDim.x + blockIdx.x;
    part[t * NPART + bid] = v;
  }
}

// ---------------------------------------------------------------------------
// Reduce 4 x 1024 partials; emit s^2*S2 - 2 s S3 + S4, s = S1/S2.
// ---------------------------------------------------------------------------
__global__ __launch_bounds__(1024) void distortion_final(
    const double* __restrict__ part, float* __restrict__ out) {
  __shared__ double red[16][4];
  const int t = threadIdx.x;
  double s[4];
  #pragma unroll
  for (int k = 0; k < 4; ++k) s[k] = part[k * NPART + t];
  #pragma unroll
  for (int off = 32; off > 0; off >>= 1)
    #pragma unroll
    for (int k = 0; k < 4; ++k) s[k] += __shfl_down(s[k], off);
  const int w = t >> 6, l = t & 63;
  if (l == 0) {
    #pragma unroll
    for (int k = 0; k < 4; ++k) red[w][k] = s[k];
  }
  __syncthreads();
  if (t == 0) {
    double S0 = 0, S1 = 0, S2 = 0, S3 = 0;
    #pragma unroll
    for (int ww = 0; ww < 16; ++ww) {
      S0 += red[ww][0]; S1 += red[ww][1]; S2 += red[ww][2]; S3 += red[ww][3];
    }
    const double sc = S0 / S1;
    const double r = (sc * sc * S1 - 2.0 * sc * S2 + S3) /
                     ((double)N_PTS * (double)N_PTS - (double)N_PTS);
    out[0] = (float)r;
  }
}

extern "C" void kernel_launch(void* const* d_in, const int* in_sizes, int n_in,
                              void* d_out, int out_size, void* d_ws, size_t ws_size,
                              hipStream_t stream) {
  const float* mapping = (const float*)d_in[0];
  const float* Dm = (const float*)d_in[1];
  float* out = (float*)d_out;
  // ws layout: nrm 16KB | part 32KB | MhiT 512KB | MloT 512KB (~1.07 MB)
  float* nrm = (float*)d_ws;
  double* part = (double*)((char*)d_ws + 16384);
  ushort* MhiT = (ushort*)((char*)d_ws + 16384 + 32768);
  ushort* MloT = (ushort*)((char*)d_ws + 16384 + 32768 + 524288);

  prep_kernel<<<dim3(N_PTS / 16), dim3(64), 0, stream>>>(mapping, MhiT, MloT, nrm);
  distortion_main<<<dim3(16, 64), dim3(256), 0, stream>>>(MhiT, MloT, Dm, nrm, part);
  distortion_final<<<1, 1024, 0, stream>>>(part, out);
}